// Round 1
// baseline (622.380 us; speedup 1.0000x reference)
//
#include <hip/hip_runtime.h>

// Problem constants: B=8, flow (B,2,H,W), depth (B,1,H,W), fp32.
constexpr int B  = 8;
constexpr int H  = 720;
constexpr int W  = 1280;
constexpr int HW = H * W;           // 921600
constexpr int N  = B * HW;          // 7372800

// Tile geometry. Inlier band: fx,fy in [-3,3). An inlier source at sx can
// only touch output columns [sx-3, sx+3] (xL=floor(sx+fx) in [sx-3,sx+2],
// xR=xL+1 clamped; same rows). So a 64x48 output tile is touched only by
// sources within the tile+3-halo region. Outliers (~0.5% for N(0,1) flow)
// take the exact global-atomic path.
constexpr int TX = 64;              // tile cols  (1280/64 = 20)
constexpr int TY = 48;              // tile rows  (720/48  = 15)
constexpr int C  = 3;
constexpr int RW = TX + 2 * C;      // 70 source cols scanned
constexpr int RH = TY + 2 * C;      // 54 source rows scanned
constexpr int RN = RW * RH;         // 3780 sources per block
constexpr int TN = TY * TX;         // 3072 outputs per block (12 per thread)

// ---------------------------------------------------------------------------
// Outlier pass: sources with fx or fy outside [-3,3). Exact, global atomics
// into zeroed ws planes. ~0.5% of pixels.
// ---------------------------------------------------------------------------
__global__ __launch_bounds__(256) void dfp_outlier(
    const float* __restrict__ flow, const float* __restrict__ depth,
    float* __restrict__ pcnt, float* __restrict__ pox, float* __restrict__ poy)
{
    int t = blockIdx.x * 256 + threadIdx.x;
    if (t >= N) return;
    int b = t / HW;
    int p = t - b * HW;
    int i = p / W;
    int j = p - i * W;

    const int fbase = b * 2 * HW;
    float fx = flow[fbase + p];
    float fy = flow[fbase + HW + p];

    // Inliers handled by the tile-scatter kernel. Predicate must match its
    // staging predicate exactly.
    if (fx >= -3.0f && fx < 3.0f && fy >= -3.0f && fy < 3.0f) return;

    float x2 = (float)j + fx;
    float y2 = (float)i + fy;
    if (!(x2 >= 0.0f && x2 <= (float)(W - 1) &&
          y2 >= 0.0f && y2 <= (float)(H - 1))) return;   // w = 0 -> no-op

    float d  = depth[t];
    int xL = (int)floorf(x2);
    int yT = (int)floorf(y2);
    int xR = min(xL + 1, W - 1);
    int yB = min(yT + 1, H - 1);
    float w = d, gx = -fx * d, gy = -fy * d;

    float* cb = pcnt + b * HW;
    float* xb = pox  + b * HW;
    float* yb = poy  + b * HW;
    int n00 = yT * W + xL, n01 = yT * W + xR, n10 = yB * W + xL, n11 = yB * W + xR;
    unsafeAtomicAdd(&cb[n00], w); unsafeAtomicAdd(&xb[n00], gx); unsafeAtomicAdd(&yb[n00], gy);
    unsafeAtomicAdd(&cb[n01], w); unsafeAtomicAdd(&xb[n01], gx); unsafeAtomicAdd(&yb[n01], gy);
    unsafeAtomicAdd(&cb[n10], w); unsafeAtomicAdd(&xb[n10], gx); unsafeAtomicAdd(&yb[n10], gy);
    unsafeAtomicAdd(&cb[n11], w); unsafeAtomicAdd(&xb[n11], gx); unsafeAtomicAdd(&yb[n11], gy);
}

// ---------------------------------------------------------------------------
// Tile-scatter kernel: block owns a 64x48 output tile as THREE LDS
// accumulator planes (cnt, sum(-fx*w), sum(-fy*w)). Each tile+halo source is
// processed ONCE: compute its 4 corner targets, ds_add_f32 the 3 values into
// any corner that lands inside the tile (corners outside are owned by the
// neighboring block, whose halo contains this source). O(sources) work vs
// the previous gather kernel's O(70 x outputs) — that one was VALU-bound at
// 76% VALUBusy / 9% HBM.
// Clamp multiplicity (xR==xL at W-1, yB==yT at H-1) is reproduced naturally
// by issuing two adds to the same address.
// ---------------------------------------------------------------------------
__global__ __launch_bounds__(256) void dfp_scatter_tile(
    const float* __restrict__ flow, const float* __restrict__ depth,
    const float* __restrict__ pcnt, const float* __restrict__ pox,
    const float* __restrict__ poy, float* __restrict__ out)
{
    __shared__ float scnt[TN];
    __shared__ float sax [TN];
    __shared__ float say [TN];

    const int tid = threadIdx.x;
    const int tx0 = blockIdx.x * TX;
    const int ty0 = blockIdx.y * TY;
    const int b   = blockIdx.z;

    #pragma unroll
    for (int r = 0; r < TN / 256; ++r) {
        int k = r * 256 + tid;
        scnt[k] = 0.0f; sax[k] = 0.0f; say[k] = 0.0f;
    }
    __syncthreads();

    const float* fxp = flow + b * 2 * HW;
    const float* fyp = fxp + HW;
    const float* dp  = depth + b * HW;

    for (int k = tid; k < RN; k += 256) {
        int ry = k / RW;                    // const divisor -> magic mul
        int rx = k - ry * RW;
        int gy = ty0 - C + ry;
        int gx = tx0 - C + rx;
        if ((unsigned)gy >= (unsigned)H || (unsigned)gx >= (unsigned)W) continue;
        int g = gy * W + gx;
        float fx = fxp[g];
        float fy = fyp[g];
        // Outliers: global pass handles them. Must match dfp_outlier exactly.
        if (!(fx >= -3.0f && fx < 3.0f && fy >= -3.0f && fy < 3.0f)) continue;
        float x2 = (float)gx + fx;
        float y2 = (float)gy + fy;
        if (!(x2 >= 0.0f && x2 <= (float)(W - 1) &&
              y2 >= 0.0f && y2 <= (float)(H - 1))) continue;   // w = 0 -> no-op
        float d  = dp[g];
        int xL = (int)floorf(x2);
        int yT = (int)floorf(y2);
        int xR = min(xL + 1, W - 1);
        int yB = min(yT + 1, H - 1);
        float w = d, ax = -fx * d, ay = -fy * d;

        int lxL = xL - tx0, lxR = xR - tx0;
        int lyT = yT - ty0, lyB = yB - ty0;
        bool cL = (unsigned)lxL < (unsigned)TX;
        bool cR = (unsigned)lxR < (unsigned)TX;
        bool cT = (unsigned)lyT < (unsigned)TY;
        bool cB = (unsigned)lyB < (unsigned)TY;

        if (cT & cL) { int o = lyT * TX + lxL;
            unsafeAtomicAdd(&scnt[o], w); unsafeAtomicAdd(&sax[o], ax); unsafeAtomicAdd(&say[o], ay); }
        if (cT & cR) { int o = lyT * TX + lxR;
            unsafeAtomicAdd(&scnt[o], w); unsafeAtomicAdd(&sax[o], ax); unsafeAtomicAdd(&say[o], ay); }
        if (cB & cL) { int o = lyB * TX + lxL;
            unsafeAtomicAdd(&scnt[o], w); unsafeAtomicAdd(&sax[o], ax); unsafeAtomicAdd(&say[o], ay); }
        if (cB & cR) { int o = lyB * TX + lxR;
            unsafeAtomicAdd(&scnt[o], w); unsafeAtomicAdd(&sax[o], ax); unsafeAtomicAdd(&say[o], ay); }
    }
    __syncthreads();

    // ---- Flush: add outlier planes, normalize, write. Coalesced (lane=lx).
    float* outx = out + b * 2 * HW;
    float* outy = outx + HW;
    const float* cb = pcnt + b * HW;
    const float* xb = pox  + b * HW;
    const float* yb = poy  + b * HW;

    #pragma unroll
    for (int r = 0; r < TN / 256; ++r) {
        int idx = r * 256 + tid;
        int ly  = idx >> 6;                 // TX = 64
        int lx  = idx & 63;
        int ga  = (ty0 + ly) * W + (tx0 + lx);
        float c  = scnt[idx] + cb[ga];
        float vx = sax [idx] + xb[ga];
        float vy = say [idx] + yb[ga];
        bool has = c > 0.0f;
        outx[ga] = has ? vx / c : 0.0f;
        outy[ga] = has ? vy / c : 0.0f;
    }
}

// ---------------------------------------------------------------------------
// Fallback path (Round-2 proven): used only if ws can't hold 3 planes.
// ---------------------------------------------------------------------------
__global__ __launch_bounds__(256) void dfp_scatter(
    const float* __restrict__ flow, const float* __restrict__ depth,
    float* __restrict__ out, float* __restrict__ count)
{
    int t = blockIdx.x * 256 + threadIdx.x;
    if (t >= N) return;
    int b = t / HW;
    int p = t - b * HW;
    int i = p / W;
    int j = p - i * W;
    const int fbase = b * 2 * HW;
    float fx = flow[fbase + p];
    float fy = flow[fbase + HW + p];
    float d  = depth[t];
    float x2 = (float)j + fx;
    float y2 = (float)i + fy;
    if (!(x2 >= 0.0f && x2 <= (float)(W - 1) &&
          y2 >= 0.0f && y2 <= (float)(H - 1))) return;
    int xL = (int)floorf(x2);
    int yT = (int)floorf(y2);
    int xR = min(xL + 1, W - 1);
    int yB = min(yT + 1, H - 1);
    float w = d, gx = -fx * w, gy = -fy * w;
    float* ox = out + fbase;
    float* oy = out + fbase + HW;
    float* cnt = count + b * HW;
    int n00 = yT * W + xL, n01 = yT * W + xR, n10 = yB * W + xL, n11 = yB * W + xR;
    unsafeAtomicAdd(&cnt[n00], w); unsafeAtomicAdd(&ox[n00], gx); unsafeAtomicAdd(&oy[n00], gy);
    unsafeAtomicAdd(&cnt[n01], w); unsafeAtomicAdd(&ox[n01], gx); unsafeAtomicAdd(&oy[n01], gy);
    unsafeAtomicAdd(&cnt[n10], w); unsafeAtomicAdd(&ox[n10], gx); unsafeAtomicAdd(&oy[n10], gy);
    unsafeAtomicAdd(&cnt[n11], w); unsafeAtomicAdd(&ox[n11], gx); unsafeAtomicAdd(&oy[n11], gy);
}

__global__ __launch_bounds__(256) void dfp_normalize(
    float* __restrict__ out, const float* __restrict__ count)
{
    int t = blockIdx.x * 256 + threadIdx.x;
    if (t >= N / 4) return;
    int t4 = t * 4;
    int b  = t4 / HW;
    int p  = t4 - b * HW;
    float4 c = *(const float4*)(count + t4);
    float* ox = out + b * 2 * HW + p;
    float* oy = ox + HW;
    float4 vx = *(const float4*)ox;
    float4 vy = *(const float4*)oy;
    vx.x = (c.x > 0.0f) ? vx.x / c.x : 0.0f;
    vx.y = (c.y > 0.0f) ? vx.y / c.y : 0.0f;
    vx.z = (c.z > 0.0f) ? vx.z / c.z : 0.0f;
    vx.w = (c.w > 0.0f) ? vx.w / c.w : 0.0f;
    vy.x = (c.x > 0.0f) ? vy.x / c.x : 0.0f;
    vy.y = (c.y > 0.0f) ? vy.y / c.y : 0.0f;
    vy.z = (c.z > 0.0f) ? vy.z / c.z : 0.0f;
    vy.w = (c.w > 0.0f) ? vy.w / c.w : 0.0f;
    *(float4*)ox = vx;
    *(float4*)oy = vy;
}

extern "C" void kernel_launch(void* const* d_in, const int* in_sizes, int n_in,
                              void* d_out, int out_size, void* d_ws, size_t ws_size,
                              hipStream_t stream)
{
    const float* flow  = (const float*)d_in[0];
    const float* depth = (const float*)d_in[1];
    float* out = (float*)d_out;

    if (ws_size >= (size_t)3 * N * sizeof(float)) {
        // Fast path: LDS-tile scatter + exact outlier pass.
        float* pcnt = (float*)d_ws;
        float* pox  = pcnt + N;
        float* poy  = pox + N;
        hipMemsetAsync(pcnt, 0, (size_t)3 * N * sizeof(float), stream);
        dfp_outlier<<<(N + 255) / 256, 256, 0, stream>>>(flow, depth, pcnt, pox, poy);
        dim3 grid(W / TX, H / TY, B);   // 20 x 15 x 8 = 2400 blocks
        dfp_scatter_tile<<<grid, 256, 0, stream>>>(flow, depth, pcnt, pox, poy, out);
    } else if (ws_size >= (size_t)N * sizeof(float)) {
        // Fallback: proven Round-2 global-atomic path.
        float* count = (float*)d_ws;
        hipMemsetAsync(out,   0, (size_t)2 * N * sizeof(float), stream);
        hipMemsetAsync(count, 0, (size_t)N * sizeof(float),     stream);
        dfp_scatter  <<<(N + 255) / 256,     256, 0, stream>>>(flow, depth, out, count);
        dfp_normalize<<<(N / 4 + 255) / 256, 256, 0, stream>>>(out, count);
    }
    // else: insufficient workspace — cannot run safely.
}